// Round 4
// baseline (891.168 us; speedup 1.0000x reference)
//
#include <hip/hip_runtime.h>
#include <hip/hip_fp16.h>

#define B_ 256
#define V_ 1000
#define P_ 200
#define L_ 50
#define H_ 384
#define H3_ 1152
#define NW_ 10
#define OUT1_OFF 12800000

typedef _Float16 half8 __attribute__((ext_vector_type(8)));
typedef float floatx4 __attribute__((ext_vector_type(4)));

// ---------------------------------------------------------------------------
// prep: f16 weight conversions, gate softmax, output-1 write.
// ---------------------------------------------------------------------------
__global__ __launch_bounds__(256) void prep_kernel(
    const float* __restrict__ gate_emb, const float* __restrict__ prog_emb,
    const float* __restrict__ w_ih, const float* __restrict__ w_hh,
    const int* __restrict__ instr, const int* __restrict__ tacts,
    float* __restrict__ g01,
    _Float16* __restrict__ whh_h, _Float16* __restrict__ wih_h,
    _Float16* __restrict__ prog_h, float* __restrict__ out)
{
  const int stride = gridDim.x * blockDim.x;
  const int tid = blockIdx.x * blockDim.x + threadIdx.x;

  for (int i = tid; i < H3_*H_; i += stride) whh_h[i] = (_Float16)w_hh[i];
  for (int i = tid; i < H3_*224; i += stride) {
    int r = i / 224, c = i - r*224;
    wih_h[i] = (_Float16)(c < P_ ? w_ih[r*P_ + c] : 0.f);  // zero-pad K to 224
  }
  for (int i = tid; i < V_*P_; i += stride) prog_h[i] = (_Float16)prog_emb[i];
  for (int i = tid; i < NW_*B_; i += stride) {
    int w = i / B_, b = i - w*B_;
    int word = instr[(1+w)*B_ + b];
    float e0 = gate_emb[word*2], e1 = gate_emb[word*2+1];
    float m = fmaxf(e0, e1);
    float a = __expf(e0-m), c = __expf(e1-m);
    float inv = 1.f/(a+c);
    g01[i*2] = a*inv; g01[i*2+1] = c*inv;
  }
  for (int i = tid; i < B_*L_; i += stride) {
    int b = i / L_, l = i - b*L_;
    out[OUT1_OFF + i] = (float)tacts[(1+l)*B_ + b];
  }
}

// ---------------------------------------------------------------------------
// gi_gemm: giv[v][n] = program_emb[v] @ w_ih.T + b_ih   (vocab-wide, once)
// ---------------------------------------------------------------------------
__global__ __launch_bounds__(256) void gi_gemm(
    const _Float16* __restrict__ prog_h, const _Float16* __restrict__ wih_h,
    const float* __restrict__ b_ih, float* __restrict__ giv)
{
  __shared__ _Float16 pA[16][232];
  const int tid = threadIdx.x;
  const int v0 = blockIdx.x * 16;
  const int n0 = blockIdx.y * 64;

  for (int i = tid; i < 16*224; i += 256) {
    int r = i / 224, c = i - r*224;
    int v = v0 + r;
    _Float16 val = (_Float16)0.f;
    if (v < V_ && c < P_) val = prog_h[v*P_ + c];
    pA[r][c] = val;
  }
  __syncthreads();

  const int wave = tid >> 6, lane = tid & 63;
  const int m = lane & 15, kg = lane >> 4;
  const int n_t = n0 + wave*16;
  floatx4 acc = {0.f, 0.f, 0.f, 0.f};
  #pragma unroll
  for (int ks = 0; ks < 7; ++ks) {
    const int kk = ks*32 + kg*8;
    half8 av = *(const half8*)&pA[m][kk];
    half8 bv = *(const half8*)&wih_h[(n_t + m)*224 + kk];
    acc = __builtin_amdgcn_mfma_f32_16x16x32_f16(av, bv, acc, 0, 0, 0);
  }
  const int nn = n_t + (lane & 15);
  const float bias = b_ih[nn];
  #pragma unroll
  for (int r = 0; r < 4; ++r) {
    int mm = v0 + kg*4 + r;
    if (mm < V_) giv[(size_t)mm*H3_ + nn] = acc[r] + bias;
  }
}

// ---------------------------------------------------------------------------
// steps16: 16 blocks x 16 batch each, 768 threads (12 waves), all 30 steps.
// w_hh lives ENTIRELY in VGPRs: each wave holds 72 B-fragments (288 VGPRs)
// covering 32 cols x 3 gates, loaded once. h kept f32 in fragment-order LDS
// (hF4f) + f16 MFMA copy (hTfh); keys pre-staged as B-fragments. All MFMA
// LDS reads are lane-consecutive 16B (conflict-free). GRU epilogue is
// wave-local (R/Z/N accs for same (b,col) in same lane).
// ---------------------------------------------------------------------------
__global__ __launch_bounds__(768) void steps16_kernel(
    float* __restrict__ S_buf,
    const _Float16* __restrict__ whh_h, const float* __restrict__ giv,
    const float* __restrict__ g01, const float* __restrict__ keys,
    const float* __restrict__ b_hh, const int* __restrict__ instr)
{
  __shared__ float    hF4f[6144];        // h f32, [part][ks][lane][comp] = [2][12][64][4]
  __shared__ _Float16 hTfh[12*64*8];     // h f16 fragments [ks][lane][8]
  __shared__ _Float16 kBfh[16*64*8];     // key B-fragments [(nt*4+ksc)][lane][8]
  __shared__ float    SrowF[16*650];     // S coeffs, per-b 650, row stride 13
  __shared__ float    sc[2][16][68];     // scores -> softmax p (in place)
  __shared__ float    nv[16][12];
  __shared__ int      wordid[16];
  __shared__ float    g0s[16], g1s[16];

  const int bid  = blockIdx.x;
  const int b0   = bid * 16;
  const int tid  = threadIdx.x;
  const int wave = tid >> 6;
  const int lane = tid & 63;
  const int m_   = lane & 15;
  const int kg   = lane >> 4;
  const int n0   = wave * 32;            // this wave's col base (per gate)

  // ---- persistent per-lane register state ----
  half8 wb[6][12];       // w_hh B-fragments [g*2+tl][ks]  (288 VGPRs)
  float bb[6];           // b_hh at this lane's 6 cols
  float gv[4][6];        // gi values per (r, g*2+tl), refreshed per word

  #pragma unroll
  for (int g = 0; g < 3; ++g) {
    #pragma unroll
    for (int tl = 0; tl < 2; ++tl) {
      const int col = g*384 + n0 + tl*16 + m_;
      bb[g*2+tl] = b_hh[col];
      #pragma unroll
      for (int ks = 0; ks < 12; ++ks)
        wb[g*2+tl][ks] = *(const half8*)&whh_h[(size_t)col*H_ + ks*32 + kg*8];
    }
  }

  // ---- one-time LDS init ----
  // h0 in fragment order: element (part,ks,l,comp) = h col ks*32+(l>>4)*8+part*4+comp
  for (int i = tid; i < 6144; i += 768) {
    const int part = i >> 11;            // /3072 -> wait 6144/2=3072; i>>11 wrong
    const int pp   = i / 3072;
    const int r    = i - pp*3072;
    const int ks   = r >> 8;             // /256
    const int r2   = r & 255;
    const int l    = r2 >> 2;
    const int comp = r2 & 3;
    const int col  = ks*32 + (l>>4)*8 + pp*4 + comp;
    (void)part;
    hF4f[i] = keys[col & 127];           // h0 = tile(scratch_keys[0], NP)
  }
  // key B-fragments: [(nt*4+ksc)][l] holds keys[nt*16+(l&15)][ksc*32+(l>>4)*8 ..+8]
  for (int i = tid; i < 1024; i += 768) {
    const int l   = i & 63;
    const int q   = i >> 6;
    const int ksc = q & 3;
    const int nt  = q >> 2;
    const int row = nt*16 + (l & 15);
    const int kb  = ksc*32 + (l >> 4)*8;
    half8 hv;
    #pragma unroll
    for (int j = 0; j < 8; ++j)
      hv[j] = (row < L_) ? (_Float16)keys[row*128 + kb + j] : (_Float16)0.f;
    *(half8*)&kBfh[i*8] = hv;
  }
  for (int i = tid; i < 16*550; i += 768) {
    const int b = i / 550, r2 = i - b*550;
    const int l = r2 / 11, j = r2 - l*11;
    SrowF[b*650 + l*13 + j] = (j == 0) ? 1.f : 0.f;
  }
  __syncthreads();

  for (int t = 0; t < 30; ++t) {
    const int widx = t / 3;
    const bool newword = (t % 3) == 0;

    if (newword && tid < 16) {
      wordid[tid] = instr[(1+widx)*B_ + b0 + tid];
      g0s[tid] = g01[(widx*B_ + b0 + tid)*2 + 0];
      g1s[tid] = g01[(widx*B_ + b0 + tid)*2 + 1];
    }
    // stage hTf (f32 fragment -> f16 fragment), one fragment per thread
    {
      float4 lo = ((const float4*)hF4f)[tid];
      float4 hi = ((const float4*)hF4f)[768 + tid];
      half8 hv = {(_Float16)lo.x, (_Float16)lo.y, (_Float16)lo.z, (_Float16)lo.w,
                  (_Float16)hi.x, (_Float16)hi.y, (_Float16)hi.z, (_Float16)hi.w};
      *(half8*)&hTfh[tid*8] = hv;
    }
    __syncthreads();   // S1: hTf + wordid ready

    // gi prefetch into registers (word boundary only; valid for 3 steps)
    if (newword) {
      #pragma unroll
      for (int r = 0; r < 4; ++r) {
        const int wd = wordid[kg*4 + r];
        #pragma unroll
        for (int g = 0; g < 3; ++g)
          #pragma unroll
          for (int tl = 0; tl < 2; ++tl)
            gv[r][g*2+tl] = giv[(size_t)wd*H3_ + g*384 + n0 + tl*16 + m_];
      }
    }

    // ---- gh GEMM: 72 register-fed MFMAs per wave ----
    floatx4 acc[6];
    #pragma unroll
    for (int c = 0; c < 6; ++c) acc[c] = (floatx4){0.f, 0.f, 0.f, 0.f};
    #pragma unroll
    for (int ks = 0; ks < 12; ++ks) {
      half8 av = *(const half8*)&hTfh[(ks*64 + lane)*8];
      #pragma unroll
      for (int c = 0; c < 6; ++c)
        acc[c] = __builtin_amdgcn_mfma_f32_16x16x32_f16(av, wb[c][ks], acc[c], 0, 0, 0);
    }

    // ---- attention scores (waves 0-7): type = wave>>2, key tile nt = wave&3 ----
    if (wave < 8) {
      const int type = wave >> 2;
      const int nt   = wave & 3;
      floatx4 as = {0.f, 0.f, 0.f, 0.f};
      #pragma unroll
      for (int ksc = 0; ksc < 4; ++ksc) {
        half8 av = *(const half8*)&hTfh[((4 + type*4 + ksc)*64 + lane)*8];
        half8 bv = *(const half8*)&kBfh[((nt*4 + ksc)*64 + lane)*8];
        as = __builtin_amdgcn_mfma_f32_16x16x32_f16(av, bv, as, 0, 0, 0);
      }
      #pragma unroll
      for (int r = 0; r < 4; ++r) sc[type][kg*4 + r][nt*16 + m_] = as[r];
    }
    __syncthreads();   // S2: scores ready

    // ---- softmax: 32 rows (type,b), waves 0-7 x 4 rows ----
    if (wave < 8) {
      #pragma unroll
      for (int q = 0; q < 4; ++q) {
        const int row = wave*4 + q;
        const int ty = row >> 4, b = row & 15;
        float val = (lane < L_) ? sc[ty][b][lane] : -1e30f;
        float mx = val;
        #pragma unroll
        for (int off = 32; off; off >>= 1) mx = fmaxf(mx, __shfl_xor(mx, off));
        float e = (lane < L_) ? __expf(val - mx) : 0.f;
        float sm = e;
        #pragma unroll
        for (int off = 32; off; off >>= 1) sm += __shfl_xor(sm, off);
        if (lane < L_) sc[ty][b][lane] = e / sm;
      }
    }
    __syncthreads();   // S3: p ready

    // ---- rv + nv (176 threads) ----
    if (tid < 176) {
      const int b = tid / 11, j = tid - b*11;
      float rv = 0.f;
      #pragma unroll 5
      for (int l = 0; l < L_; ++l) rv += sc[0][b][l] * SrowF[b*650 + l*13 + j];
      nv[b][j] = g1s[b]*rv + ((j == 1 + widx) ? g0s[b] : 0.f);
    }
    __syncthreads();   // S4: nv ready

    // ---- S update (in place) ----
    for (int i = tid; i < 16*550; i += 768) {
      const int b = i / 550, r2 = i - b*550;
      const int l = r2 / 11, j = r2 - l*11;
      const float wm = sc[1][b][l];
      const int a = b*650 + l*13 + j;
      SrowF[a] = wm*nv[b][j] + (1.f - wm)*SrowF[a];
    }

    // ---- fused GRU epilogue (wave-local: R/Z/N in acc[0..5]) ----
    #pragma unroll
    for (int tl = 0; tl < 2; ++tl) {
      const int sub  = tl*16 + m_;        // col within wave's 32-col group
      const int kg4  = sub >> 3;
      const int j    = sub & 7;
      const int part = j >> 2;
      const int comp = j & 3;
      #pragma unroll
      for (int r = 0; r < 4; ++r) {
        const int b = kg*4 + r;
        const int ha = ((part*12 + wave)*64 + kg4*16 + b)*4 + comp;
        const float ghr = acc[0*2+tl][r] + bb[0*2+tl];
        const float ghz = acc[1*2+tl][r] + bb[1*2+tl];
        const float ghn = acc[2*2+tl][r] + bb[2*2+tl];
        const float rg = 1.f/(1.f + __expf(-(gv[r][0*2+tl] + ghr)));
        const float z  = 1.f/(1.f + __expf(-(gv[r][1*2+tl] + ghz)));
        const float x2 = gv[r][2*2+tl] + rg*ghn;
        const float nn = 2.f/(1.f + __expf(-2.f*x2)) - 1.f;   // tanh
        const float hold = hF4f[ha];
        const float hnew = (1.f - z)*nn + z*hold;
        hF4f[ha] = g0s[b]*hold + g1s[b]*hnew;
      }
    }
    __syncthreads();   // S5: hF4/Srow complete before next staging
  }

  // spill S coefficients for the epilogue kernels
  for (int i = tid; i < 16*550; i += 768) {
    const int b = i / 550, r2 = i - b*550;
    const int l = r2 / 11, j = r2 - l*11;
    S_buf[(size_t)(b0 + b)*600 + l*12 + j] = SrowF[b*650 + l*13 + j];
  }
}

// ---------------------------------------------------------------------------
// lse: per (b,l) log-sum-exp over the 1000-v reconstruction.
// ---------------------------------------------------------------------------
__global__ __launch_bounds__(512) void lse_kernel(
    const float* __restrict__ S_buf, const float* __restrict__ prim_emb,
    const float* __restrict__ iv_g, const int* __restrict__ instr,
    float* __restrict__ ls_buf)
{
  __shared__ float prim[10][1000];
  __shared__ float iv[1000];
  __shared__ float Sr[50][12];
  __shared__ int wds[10];

  const int b = blockIdx.x;
  const int tid = threadIdx.x;

  if (tid < 10) wds[tid] = instr[(1+tid)*B_ + b];
  for (int i = tid; i < 600; i += 512) Sr[i/12][i%12] = S_buf[(size_t)b*600 + i];
  __syncthreads();
  for (int wi = 0; wi < 10; ++wi) {
    const float4* __restrict__ src = (const float4*)(prim_emb + (size_t)wds[wi]*V_);
    for (int i = tid; i < 250; i += 512) ((float4*)prim[wi])[i] = src[i];
  }
  for (int i = tid; i < 250; i += 512) ((float4*)iv)[i] = ((const float4*)iv_g)[i];
  __syncthreads();

  const int wave = tid >> 6, lane = tid & 63;
  for (int l = wave; l < L_; l += 8) {
    float c0 = Sr[l][0];
    float cw[10];
    #pragma unroll
    for (int wi = 0; wi < 10; ++wi) cw[wi] = Sr[l][1+wi];
    float sv[16];
    float mx = -1e30f;
    #pragma unroll
    for (int j = 0; j < 16; ++j) {
      int v = lane + 64*j;
      float s = -1e30f;
      if (v < V_) {
        s = c0 * iv[v];
        #pragma unroll
        for (int wi = 0; wi < 10; ++wi) s += cw[wi]*prim[wi][v];
      }
      sv[j] = s;
      mx = fmaxf(mx, s);
    }
    #pragma unroll
    for (int off = 32; off; off >>= 1) mx = fmaxf(mx, __shfl_xor(mx, off));
    float se = 0.f;
    #pragma unroll
    for (int j = 0; j < 16; ++j) {
      int v = lane + 64*j;
      if (v < V_) se += __expf(sv[j] - mx);
    }
    #pragma unroll
    for (int off = 32; off; off >>= 1) se += __shfl_xor(se, off);
    if (lane == 0) ls_buf[b*L_ + l] = mx + __logf(se);
  }
}

// ---------------------------------------------------------------------------
// write: per (v-chunk of 125, b) block computes sv - lse and stores a
// contiguous 25 KB region (fully coalesced).
// ---------------------------------------------------------------------------
__global__ __launch_bounds__(256) void write_kernel(
    const float* __restrict__ S_buf, const float* __restrict__ prim_emb,
    const float* __restrict__ iv_g, const float* __restrict__ ls_buf,
    const int* __restrict__ instr, float* __restrict__ out)
{
  __shared__ float SrT[11][52];
  __shared__ float lss[52];
  __shared__ float primc[10][128];
  __shared__ float ivc[128];
  __shared__ int wds[10];

  const int cx = blockIdx.x;      // 0..7
  const int b  = blockIdx.y;      // 0..255
  const int v0 = cx * 125;
  const int tid = threadIdx.x;

  if (tid < 10) wds[tid] = instr[(1+tid)*B_ + b];
  if (tid < 50) lss[tid] = ls_buf[b*L_ + tid];
  for (int i = tid; i < 550; i += 256) {
    int l = i / 11, j = i - l*11;
    SrT[j][l] = S_buf[(size_t)b*600 + l*12 + j];
  }
  for (int i = tid; i < 125; i += 256) ivc[i] = iv_g[v0 + i];
  __syncthreads();
  for (int i = tid; i < 1250; i += 256) {
    int wi = i / 125, j = i - wi*125;
    primc[wi][j] = prim_emb[(size_t)wds[wi]*V_ + v0 + j];
  }
  __syncthreads();

  float* __restrict__ dst = out + (size_t)b*50000 + (size_t)v0*50;
  for (int e = tid; e < 125*50; e += 256) {
    const int v = e / 50, l = e - v*50;
    float s = SrT[0][l]*ivc[v];
    #pragma unroll
    for (int wi = 0; wi < 10; ++wi) s += SrT[1+wi][l]*primc[wi][v];
    dst[e] = s - lss[l];
  }
}

// ---------------------------------------------------------------------------
extern "C" void kernel_launch(void* const* d_in, const int* in_sizes, int n_in,
                              void* d_out, int out_size, void* d_ws, size_t ws_size,
                              hipStream_t stream)
{
  (void)in_sizes; (void)n_in; (void)out_size; (void)ws_size;
  const float* gate_emb = (const float*)d_in[0];
  const float* prog_emb = (const float*)d_in[1];
  const float* prim_emb = (const float*)d_in[2];
  const float* sk       = (const float*)d_in[3];
  const float* iv       = (const float*)d_in[4];
  const float* w_ih     = (const float*)d_in[5];
  const float* w_hh     = (const float*)d_in[6];
  const float* b_ih     = (const float*)d_in[7];
  const float* b_hh     = (const float*)d_in[8];
  const int*   instr    = (const int*)d_in[9];
  const int*   tacts    = (const int*)d_in[10];
  float* out = (float*)d_out;

  float* ws     = (float*)d_ws;
  float* S_buf  = ws;                        // 256*600 f32
  float* g01    = S_buf + B_*600;            // 5120 f32
  float* ls_buf = g01 + NW_*B_*2;            // 256*50 f32
  float* giv    = ls_buf + B_*L_;            // 1000*1152 f32
  _Float16* whh_h  = (_Float16*)(giv + (size_t)V_*H3_);
  _Float16* wih_h  = whh_h + (size_t)H3_*H_;
  _Float16* prog_h = wih_h + (size_t)H3_*224;

  hipLaunchKernelGGL(prep_kernel, dim3(1024), dim3(256), 0, stream,
      gate_emb, prog_emb, w_ih, w_hh, instr, tacts,
      g01, whh_h, wih_h, prog_h, out);

  hipLaunchKernelGGL(gi_gemm, dim3(63, 18), dim3(256), 0, stream,
      prog_h, wih_h, b_ih, giv);

  hipLaunchKernelGGL(steps16_kernel, dim3(16), dim3(768), 0, stream,
      S_buf, whh_h, giv, g01, sk, b_hh, instr);

  hipLaunchKernelGGL(lse_kernel, dim3(256), dim3(512), 0, stream,
      S_buf, prim_emb, iv, instr, ls_buf);

  hipLaunchKernelGGL(write_kernel, dim3(8, 256), dim3(256), 0, stream,
      S_buf, prim_emb, iv, ls_buf, instr, out);
}

// Round 5
// 510.935 us; speedup vs baseline: 1.7442x; 1.7442x over previous
//
#include <hip/hip_runtime.h>
#include <hip/hip_fp16.h>
#include <hip/hip_fp8.h>

#define B_ 256
#define V_ 1000
#define P_ 200
#define L_ 50
#define H_ 384
#define H3_ 1152
#define NW_ 10
#define OUT1_OFF 12800000

typedef _Float16 half8 __attribute__((ext_vector_type(8)));
typedef float floatx4 __attribute__((ext_vector_type(4)));

// ---------------------------------------------------------------------------
// prep: fp8 fragment-order w_hh, f16 gi-GEMM operands, gate softmax, out1.
// whh8 byte i: e=i&7, l=(i>>3)&63, kc=(i>>9)%12, w=(i>>9)/12%12, s=(i>>9)/144
//   row=(s>>1)*384+(s&1)*192+16w+(l&15), col=kc*32+(l>>4)*8+e
// ---------------------------------------------------------------------------
__global__ __launch_bounds__(256) void prep_kernel(
    const float* __restrict__ gate_emb, const float* __restrict__ prog_emb,
    const float* __restrict__ w_ih, const float* __restrict__ w_hh,
    const int* __restrict__ instr, const int* __restrict__ tacts,
    float* __restrict__ g01, unsigned char* __restrict__ whh8,
    _Float16* __restrict__ wih_h, _Float16* __restrict__ prog_h,
    float* __restrict__ out)
{
  const int stride = gridDim.x * blockDim.x;
  const int tid = blockIdx.x * blockDim.x + threadIdx.x;

  for (int i = tid; i < H3_*H_; i += stride) {
    const int e = i & 7, l = (i >> 3) & 63, q = i >> 9;
    const int kc = q % 12, q2 = q / 12;
    const int w = q2 % 12, s = q2 / 12;
    const int row = (s >> 1)*384 + (s & 1)*192 + 16*w + (l & 15);
    const int col = kc*32 + (l >> 4)*8 + e;
    __hip_fp8_e4m3 qv(w_hh[row*H_ + col]);
    whh8[i] = qv.__x;
  }
  for (int i = tid; i < H3_*224; i += stride) {
    int r = i / 224, c = i - r*224;
    wih_h[i] = (_Float16)(c < P_ ? w_ih[r*P_ + c] : 0.f);
  }
  for (int i = tid; i < V_*P_; i += stride) prog_h[i] = (_Float16)prog_emb[i];
  for (int i = tid; i < NW_*B_; i += stride) {
    int w = i / B_, b = i - w*B_;
    int word = instr[(1+w)*B_ + b];
    float e0 = gate_emb[word*2], e1 = gate_emb[word*2+1];
    float m = fmaxf(e0, e1);
    float a = __expf(e0-m), c = __expf(e1-m);
    float inv = 1.f/(a+c);
    g01[i*2] = a*inv; g01[i*2+1] = c*inv;
  }
  for (int i = tid; i < B_*L_; i += stride) {
    int b = i / L_, l = i - b*L_;
    out[OUT1_OFF + i] = (float)tacts[(1+l)*B_ + b];
  }
}

// ---------------------------------------------------------------------------
// gi_gemm: giv[v][n] = program_emb[v] @ w_ih.T + b_ih   (vocab-wide, once)
// ---------------------------------------------------------------------------
__global__ __launch_bounds__(256) void gi_gemm(
    const _Float16* __restrict__ prog_h, const _Float16* __restrict__ wih_h,
    const float* __restrict__ b_ih, float* __restrict__ giv)
{
  __shared__ _Float16 pA[16][232];
  const int tid = threadIdx.x;
  const int v0 = blockIdx.x * 16;
  const int n0 = blockIdx.y * 64;

  for (int i = tid; i < 16*224; i += 256) {
    int r = i / 224, c = i - r*224;
    int v = v0 + r;
    _Float16 val = (_Float16)0.f;
    if (v < V_ && c < P_) val = prog_h[v*P_ + c];
    pA[r][c] = val;
  }
  __syncthreads();

  const int wave = tid >> 6, lane = tid & 63;
  const int m = lane & 15, kg = lane >> 4;
  const int n_t = n0 + wave*16;
  floatx4 acc = {0.f, 0.f, 0.f, 0.f};
  #pragma unroll
  for (int ks = 0; ks < 7; ++ks) {
    const int kk = ks*32 + kg*8;
    half8 av = *(const half8*)&pA[m][kk];
    half8 bv = *(const half8*)&wih_h[(n_t + m)*224 + kk];
    acc = __builtin_amdgcn_mfma_f32_16x16x32_f16(av, bv, acc, 0, 0, 0);
  }
  const int nn = n_t + m;
  const float bias = b_ih[nn];
  #pragma unroll
  for (int r = 0; r < 4; ++r) {
    int mm = v0 + kg*4 + r;
    if (mm < V_) giv[(size_t)mm*H3_ + nn] = acc[r] + bias;
  }
}

// ---------------------------------------------------------------------------
// steps: pure GRU recurrence, 16 blocks x 768 threads (12 waves).
// Weights stream via global_load_lds into 2x73.7KB LDS buffers, 6 slices per
// step, double-buffered (prefetch of slice s+1 overlaps compute of slice s;
// weights are step-invariant so the stream never depends on h).
// h lives in registers (hreg f32) + an fp8 A-fragment LDS image (hA).
// Per step dumps h[:,128:384] (pre-update state of the NEXT step index) to
// global as f16 for the decoupled attention kernel.
// ---------------------------------------------------------------------------
__global__ __launch_bounds__(768, 1) void steps_kernel(
    const unsigned long long* __restrict__ whh8, const float* __restrict__ giv,
    const float* __restrict__ g01, const float* __restrict__ keys,
    const float* __restrict__ bhh, const int* __restrict__ instr,
    _Float16* __restrict__ hrw16)
{
  __shared__ unsigned long long wA[2][9216];   // 147456 B  [buf][(w*12+kc)*64+lane]
  __shared__ unsigned long long hA[768];       // 6144 B    [ks*64+lane]

  const int bid = blockIdx.x, b0 = bid*16, tid = threadIdx.x;
  const int w = tid >> 6, lane = tid & 63, m_ = lane & 15, kg = lane >> 4;
  const int c0 = 16*w + m_, c1 = 192 + 16*w + m_;

  float hreg[2][4];
  float bb[6];
  float gvv[4][6];
  float g0r[4], g1r[4];
  int   wdr[4];

  #pragma unroll
  for (int g = 0; g < 3; ++g) {
    bb[g*2]   = bhh[g*384 + c0];
    bb[g*2+1] = bhh[g*384 + c1];
  }

  // h0 = tile(scratch_keys[0], 3)
  const float h0a = keys[c0 & 127];
  const float h0b = keys[c1 & 127];
  #pragma unroll
  for (int r = 0; r < 4; ++r) { hreg[0][r] = h0a; hreg[1][r] = h0b; }

  // write initial hA fp8 image + hrw16[0]
  #pragma unroll
  for (int half = 0; half < 2; ++half) {
    const int c = half ? c1 : c0;
    const int base = (c >> 5)*512 + ((c >> 3) & 3)*128 + (c & 7);
    #pragma unroll
    for (int r = 0; r < 4; ++r) {
      const int b = kg*4 + r;
      __hip_fp8_e4m3 q(hreg[half][r]);
      ((unsigned char*)hA)[base + b*8] = q.__x;
      if (c >= 128)
        hrw16[((size_t)(0*16 + bid)*256 + (c - 128))*16 + b] = (_Float16)hreg[half][r];
    }
  }
  __syncthreads();

  // DMA prologue: slice 0 -> buf 0
  {
    const unsigned long long* gs = whh8 + (size_t)0*9216 + w*768;
    #pragma unroll
    for (int i = 0; i < 6; ++i)
      __builtin_amdgcn_global_load_lds((const unsigned int*)(gs + i*128 + lane*2),
                                       (unsigned int*)&wA[0][w*768 + i*128], 16, 0, 0);
  }

  unsigned long long av[12];
  floatx4 acc[6];

  for (int t = 0; t < 30; ++t) {
    const int widx = t / 3;
    #pragma unroll
    for (int s = 0; s < 6; ++s) {
      const int p = s & 1;          // sigma = 6t+s; 6t even -> buf parity = s&1

      asm volatile("s_waitcnt vmcnt(0)" ::: "memory");
      __syncthreads();

      if (t < 29 || s < 5) {
        const int sn = (s + 1) % 6;
        const int pn = p ^ 1;
        const unsigned long long* gs = whh8 + (size_t)sn*9216 + w*768;
        #pragma unroll
        for (int i = 0; i < 6; ++i)
          __builtin_amdgcn_global_load_lds((const unsigned int*)(gs + i*128 + lane*2),
                                           (unsigned int*)&wA[pn][w*768 + i*128], 16, 0, 0);
      }

      if (s == 0) {
        if (t % 3 == 0) {
          #pragma unroll
          for (int r = 0; r < 4; ++r) {
            const int b = b0 + kg*4 + r;
            wdr[r] = instr[(1+widx)*B_ + b];
            g0r[r] = g01[(widx*B_ + b)*2 + 0];
            g1r[r] = g01[(widx*B_ + b)*2 + 1];
          }
          #pragma unroll
          for (int r = 0; r < 4; ++r) {
            const float* gp = giv + (size_t)wdr[r]*H3_;
            #pragma unroll
            for (int g = 0; g < 3; ++g) {
              gvv[r][g*2]   = gp[g*384 + c0];
              gvv[r][g*2+1] = gp[g*384 + c1];
            }
          }
        }
        #pragma unroll
        for (int ks = 0; ks < 12; ++ks) av[ks] = hA[ks*64 + lane];
        #pragma unroll
        for (int c = 0; c < 6; ++c) acc[c] = (floatx4){0.f, 0.f, 0.f, 0.f};
      }

      // compute slice s: this wave's 16-col tile, 12 K-chunks
      #pragma unroll
      for (int kc = 0; kc < 12; ++kc) {
        unsigned long long bf = wA[p][(w*12 + kc)*64 + lane];
        acc[s] = __builtin_amdgcn_mfma_f32_16x16x32_fp8_fp8(
            (long)av[kc], (long)bf, acc[s], 0, 0, 0);
      }

      if (s == 5) {
        // fused GRU epilogue (wave-local; acc[g*2+half])
        #pragma unroll
        for (int half = 0; half < 2; ++half) {
          #pragma unroll
          for (int r = 0; r < 4; ++r) {
            const float ghr = acc[0 + half][r] + bb[0 + half];
            const float ghz = acc[2 + half][r] + bb[2 + half];
            const float ghn = acc[4 + half][r] + bb[4 + half];
            const float rg = 1.f/(1.f + __expf(-(gvv[r][0 + half] + ghr)));
            const float z  = 1.f/(1.f + __expf(-(gvv[r][2 + half] + ghz)));
            const float x2 = gvv[r][4 + half] + rg*ghn;
            const float nn = 2.f/(1.f + __expf(-2.f*x2)) - 1.f;   // tanh
            const float hold = hreg[half][r];
            const float hnew = (1.f - z)*nn + z*hold;
            hreg[half][r] = g0r[r]*hold + g1r[r]*hnew;
          }
        }
        // write new fp8 image + dump slices for step t+1
        #pragma unroll
        for (int half = 0; half < 2; ++half) {
          const int c = half ? c1 : c0;
          const int base = (c >> 5)*512 + ((c >> 3) & 3)*128 + (c & 7);
          #pragma unroll
          for (int r = 0; r < 4; ++r) {
            const int b = kg*4 + r;
            __hip_fp8_e4m3 q(hreg[half][r]);
            ((unsigned char*)hA)[base + b*8] = q.__x;
            if (t + 1 < 30 && c >= 128)
              hrw16[((size_t)((t+1)*16 + bid)*256 + (c - 128))*16 + b] = (_Float16)hreg[half][r];
          }
        }
      }
    }
  }
}

// ---------------------------------------------------------------------------
// attnS: decoupled attention/S recurrence. One block per batch element,
// 256 threads (4 waves). Reads the h slices dumped by steps_kernel; keeps
// S coefficients in LDS across all 30 steps; writes final S to S_buf.
// ---------------------------------------------------------------------------
__global__ __launch_bounds__(256) void attnS_kernel(
    const _Float16* __restrict__ hrw16, const float* __restrict__ keys,
    const float* __restrict__ g01, float* __restrict__ S_buf)
{
  __shared__ float keysT[128][52];
  __shared__ float Sr[50][13];
  __shared__ float hrF[256];
  __shared__ float part[4][64];
  __shared__ float pL[64], wmL[64], nvs[12];

  const int b = blockIdx.x, g = b >> 4, bl = b & 15;
  const int tid = threadIdx.x, wv = tid >> 6, lane = tid & 63;

  for (int i = tid; i < 128*L_; i += 256) {
    int k = i / L_, l = i - k*L_;
    keysT[k][l] = keys[l*128 + k];
  }
  for (int i = tid; i < 550; i += 256) Sr[i/11][i%11] = ((i % 11) == 0) ? 1.f : 0.f;
  __syncthreads();

  for (int t = 0; t < 30; ++t) {
    const int widx = t / 3;
    hrF[tid] = (float)hrw16[((size_t)(t*16 + g)*256 + tid)*16 + bl];
    __syncthreads();

    // partial dots: wave -> (type = wv>>1, k-half = wv&1)
    {
      const int ty = wv >> 1, kh = wv & 1;
      float s = 0.f;
      if (lane < L_) {
        #pragma unroll
        for (int k = 0; k < 64; ++k)
          s += hrF[ty*128 + kh*64 + k] * keysT[kh*64 + k][lane];
      }
      part[wv][lane] = s;
    }
    __syncthreads();

    if (wv == 0 || wv == 2) {
      const int ty = wv >> 1;
      float val = (lane < L_) ? part[ty*2][lane] + part[ty*2+1][lane] : -1e30f;
      float mx = val;
      #pragma unroll
      for (int off = 32; off; off >>= 1) mx = fmaxf(mx, __shfl_xor(mx, off));
      float e = (lane < L_) ? __expf(val - mx) : 0.f;
      float sm = e;
      #pragma unroll
      for (int off = 32; off; off >>= 1) sm += __shfl_xor(sm, off);
      if (lane < L_) {
        if (ty == 0) pL[lane] = e / sm; else wmL[lane] = e / sm;
      }
    }
    __syncthreads();

    if (tid < 11) {
      float rv = 0.f;
      #pragma unroll 5
      for (int l = 0; l < L_; ++l) rv += pL[l]*Sr[l][tid];
      const float g0 = g01[(widx*B_ + b)*2 + 0];
      const float g1 = g01[(widx*B_ + b)*2 + 1];
      nvs[tid] = g1*rv + ((tid == 1 + widx) ? g0 : 0.f);
    }
    __syncthreads();

    for (int i = tid; i < 550; i += 256) {
      const int l = i / 11, j = i - l*11;
      Sr[l][j] = wmL[l]*nvs[j] + (1.f - wmL[l])*Sr[l][j];
    }
    __syncthreads();
  }

  for (int i = tid; i < 550; i += 256) {
    const int l = i / 11, j = i - l*11;
    S_buf[(size_t)b*600 + l*12 + j] = Sr[l][j];
  }
}

// ---------------------------------------------------------------------------
// lse: per (b,l) log-sum-exp over the 1000-v reconstruction.
// ---------------------------------------------------------------------------
__global__ __launch_bounds__(512) void lse_kernel(
    const float* __restrict__ S_buf, const float* __restrict__ prim_emb,
    const float* __restrict__ iv_g, const int* __restrict__ instr,
    float* __restrict__ ls_buf)
{
  __shared__ float prim[10][1000];
  __shared__ float iv[1000];
  __shared__ float Sr[50][12];
  __shared__ int wds[10];

  const int b = blockIdx.x;
  const int tid = threadIdx.x;

  if (tid < 10) wds[tid] = instr[(1+tid)*B_ + b];
  for (int i = tid; i < 600; i += 512) Sr[i/12][i%12] = S_buf[(size_t)b*600 + i];
  __syncthreads();
  for (int wi = 0; wi < 10; ++wi) {
    const float4* __restrict__ src = (const float4*)(prim_emb + (size_t)wds[wi]*V_);
    for (int i = tid; i < 250; i += 512) ((float4*)prim[wi])[i] = src[i];
  }
  for (int i = tid; i < 250; i += 512) ((float4*)iv)[i] = ((const float4*)iv_g)[i];
  __syncthreads();

  const int wave = tid >> 6, lane = tid & 63;
  for (int l = wave; l < L_; l += 8) {
    float c0 = Sr[l][0];
    float cw[10];
    #pragma unroll
    for (int wi = 0; wi < 10; ++wi) cw[wi] = Sr[l][1+wi];
    float sv[16];
    float mx = -1e30f;
    #pragma unroll
    for (int j = 0; j < 16; ++j) {
      int v = lane + 64*j;
      float s = -1e30f;
      if (v < V_) {
        s = c0 * iv[v];
        #pragma unroll
        for (int wi = 0; wi < 10; ++wi) s += cw[wi]*prim[wi][v];
      }
      sv[j] = s;
      mx = fmaxf(mx, s);
    }
    #pragma unroll
    for (int off = 32; off; off >>= 1) mx = fmaxf(mx, __shfl_xor(mx, off));
    float se = 0.f;
    #pragma unroll
    for (int j = 0; j < 16; ++j) {
      int v = lane + 64*j;
      if (v < V_) se += __expf(sv[j] - mx);
    }
    #pragma unroll
    for (int off = 32; off; off >>= 1) se += __shfl_xor(se, off);
    if (lane == 0) ls_buf[b*L_ + l] = mx + __logf(se);
  }
}

// ---------------------------------------------------------------------------
// write: per (v-chunk of 125, b) block computes sv - lse, contiguous stores.
// ---------------------------------------------------------------------------
__global__ __launch_bounds__(256) void write_kernel(
    const float* __restrict__ S_buf, const float* __restrict__ prim_emb,
    const float* __restrict__ iv_g, const float* __restrict__ ls_buf,
    const int* __restrict__ instr, float* __restrict__ out)
{
  __shared__ float SrT[11][52];
  __shared__ float lss[52];
  __shared__ float primc[10][128];
  __shared__ float ivc[128];
  __shared__ int wds[10];

  const int cx = blockIdx.x;      // 0..7
  const int b  = blockIdx.y;      // 0..255
  const int v0 = cx * 125;
  const int tid = threadIdx.x;

  if (tid < 10) wds[tid] = instr[(1+tid)*B_ + b];
  if (tid < 50) lss[tid] = ls_buf[b*L_ + tid];
  for (int i = tid; i < 550; i += 256) {
    int l = i / 11, j = i - l*11;
    SrT[j][l] = S_buf[(size_t)b*600 + l*12 + j];
  }
  for (int i = tid; i < 125; i += 256) ivc[i] = iv_g[v0 + i];
  __syncthreads();
  for (int i = tid; i < 1250; i += 256) {
    int wi = i / 125, j = i - wi*125;
    primc[wi][j] = prim_emb[(size_t)wds[wi]*V_ + v0 + j];
  }
  __syncthreads();

  float* __restrict__ dst = out + (size_t)b*50000 + (size_t)v0*50;
  for (int e = tid; e < 125*50; e += 256) {
    const int v = e / 50, l = e - v*50;
    float s = SrT[0][l]*ivc[v];
    #pragma unroll
    for (int wi = 0; wi < 10; ++wi) s += SrT[1+wi][l]*primc[wi][v];
    dst[e] = s - lss[l];
  }
}

// ---------------------------------------------------------------------------
extern "C" void kernel_launch(void* const* d_in, const int* in_sizes, int n_in,
                              void* d_out, int out_size, void* d_ws, size_t ws_size,
                              hipStream_t stream)
{
  (void)in_sizes; (void)n_in; (void)out_size; (void)ws_size;
  const float* gate_emb = (const float*)d_in[0];
  const float* prog_emb = (const float*)d_in[1];
  const float* prim_emb = (const float*)d_in[2];
  const float* sk       = (const float*)d_in[3];
  const float* iv       = (const float*)d_in[4];
  const float* w_ih     = (const float*)d_in[5];
  const float* w_hh     = (const float*)d_in[6];
  const float* b_ih     = (const float*)d_in[7];
  const float* b_hh     = (const float*)d_in[8];
  const int*   instr    = (const int*)d_in[9];
  const int*   tacts    = (const int*)d_in[10];
  float* out = (float*)d_out;

  float* ws     = (float*)d_ws;
  float* S_buf  = ws;                          // 256*600 f32
  float* g01    = S_buf + B_*600;              // 5120 f32
  float* ls_buf = g01 + NW_*B_*2;              // 12800 f32
  float* giv    = ls_buf + B_*L_;              // 1,152,000 f32
  unsigned long long* whh8 = (unsigned long long*)(giv + (size_t)V_*H3_);  // 55296 u64
  _Float16* wih_h  = (_Float16*)(whh8 + 55296);              // 1152*224 f16
  _Float16* prog_h = wih_h + (size_t)H3_*224;                // 200000 f16
  _Float16* hrw16  = prog_h + (size_t)V_*P_;                 // 30*16*256*16 f16

  hipLaunchKernelGGL(prep_kernel, dim3(1024), dim3(256), 0, stream,
      gate_emb, prog_emb, w_ih, w_hh, instr, tacts,
      g01, (unsigned char*)whh8, wih_h, prog_h, out);

  hipLaunchKernelGGL(gi_gemm, dim3(63, 18), dim3(256), 0, stream,
      prog_h, wih_h, b_ih, giv);

  hipLaunchKernelGGL(steps_kernel, dim3(16), dim3(768), 0, stream,
      whh8, giv, g01, sk, b_hh, instr, hrw16);

  hipLaunchKernelGGL(attnS_kernel, dim3(256), dim3(256), 0, stream,
      hrw16, sk, g01, S_buf);

  hipLaunchKernelGGL(lse_kernel, dim3(256), dim3(512), 0, stream,
      S_buf, prim_emb, iv, instr, ls_buf);

  hipLaunchKernelGGL(write_kernel, dim3(8, 256), dim3(256), 0, stream,
      S_buf, prim_emb, iv, ls_buf, instr, out);
}

// Round 6
// 427.714 us; speedup vs baseline: 2.0836x; 1.1946x over previous
//
#include <hip/hip_runtime.h>
#include <hip/hip_fp16.h>
#include <hip/hip_fp8.h>

#define B_ 256
#define V_ 1000
#define P_ 200
#define L_ 50
#define H_ 384
#define H3_ 1152
#define NW_ 10
#define OUT1_OFF 12800000

typedef _Float16 half8 __attribute__((ext_vector_type(8)));
typedef _Float16 half4_t __attribute__((ext_vector_type(4)));
typedef float floatx4 __attribute__((ext_vector_type(4)));

#define VMWAIT(n) asm volatile("s_waitcnt vmcnt(" #n ")" ::: "memory")
#define SB0() __builtin_amdgcn_sched_barrier(0)

// ---------------------------------------------------------------------------
// prep: fp8 fragment-order w_hh, f16 gi-GEMM operands, gate softmax, out1.
// whh8 byte i: e=i&7, l=(i>>3)&63, kc=(i>>9)%12, w=(i>>9)/12%12, s=(i>>9)/144
//   row=(s>>1)*384+(s&1)*192+16w+(l&15), col=kc*32+(l>>4)*8+e
// ---------------------------------------------------------------------------
__global__ __launch_bounds__(256) void prep_kernel(
    const float* __restrict__ gate_emb, const float* __restrict__ prog_emb,
    const float* __restrict__ w_ih, const float* __restrict__ w_hh,
    const int* __restrict__ instr, const int* __restrict__ tacts,
    float* __restrict__ g01, unsigned char* __restrict__ whh8,
    _Float16* __restrict__ wih_h, _Float16* __restrict__ prog_h,
    float* __restrict__ out)
{
  const int stride = gridDim.x * blockDim.x;
  const int tid = blockIdx.x * blockDim.x + threadIdx.x;

  for (int i = tid; i < H3_*H_; i += stride) {
    const int e = i & 7, l = (i >> 3) & 63, q = i >> 9;
    const int kc = q % 12, q2 = q / 12;
    const int w = q2 % 12, s = q2 / 12;
    const int row = (s >> 1)*384 + (s & 1)*192 + 16*w + (l & 15);
    const int col = kc*32 + (l >> 4)*8 + e;
    __hip_fp8_e4m3 qv(w_hh[row*H_ + col]);
    whh8[i] = qv.__x;
  }
  for (int i = tid; i < H3_*224; i += stride) {
    int r = i / 224, c = i - r*224;
    wih_h[i] = (_Float16)(c < P_ ? w_ih[r*P_ + c] : 0.f);
  }
  for (int i = tid; i < V_*P_; i += stride) prog_h[i] = (_Float16)prog_emb[i];
  for (int i = tid; i < NW_*B_; i += stride) {
    int w = i / B_, b = i - w*B_;
    int word = instr[(1+w)*B_ + b];
    float e0 = gate_emb[word*2], e1 = gate_emb[word*2+1];
    float m = fmaxf(e0, e1);
    float a = __expf(e0-m), c = __expf(e1-m);
    float inv = 1.f/(a+c);
    g01[i*2] = a*inv; g01[i*2+1] = c*inv;
  }
  for (int i = tid; i < B_*L_; i += stride) {
    int b = i / L_, l = i - b*L_;
    out[OUT1_OFF + i] = (float)tacts[(1+l)*B_ + b];
  }
}

// ---------------------------------------------------------------------------
// gi_gemm: giv[v][n] = program_emb[v] @ w_ih.T + b_ih   (vocab-wide, once)
// ---------------------------------------------------------------------------
__global__ __launch_bounds__(256) void gi_gemm(
    const _Float16* __restrict__ prog_h, const _Float16* __restrict__ wih_h,
    const float* __restrict__ b_ih, float* __restrict__ giv)
{
  __shared__ _Float16 pA[16][232];
  const int tid = threadIdx.x;
  const int v0 = blockIdx.x * 16;
  const int n0 = blockIdx.y * 64;

  for (int i = tid; i < 16*224; i += 256) {
    int r = i / 224, c = i - r*224;
    int v = v0 + r;
    _Float16 val = (_Float16)0.f;
    if (v < V_ && c < P_) val = prog_h[v*P_ + c];
    pA[r][c] = val;
  }
  __syncthreads();

  const int wave = tid >> 6, lane = tid & 63;
  const int m = lane & 15, kg = lane >> 4;
  const int n_t = n0 + wave*16;
  floatx4 acc = {0.f, 0.f, 0.f, 0.f};
  #pragma unroll
  for (int ks = 0; ks < 7; ++ks) {
    const int kk = ks*32 + kg*8;
    half8 av = *(const half8*)&pA[m][kk];
    half8 bv = *(const half8*)&wih_h[(n_t + m)*224 + kk];
    acc = __builtin_amdgcn_mfma_f32_16x16x32_f16(av, bv, acc, 0, 0, 0);
  }
  const int nn = n_t + m;
  const float bias = b_ih[nn];
  #pragma unroll
  for (int r = 0; r < 4; ++r) {
    int mm = v0 + kg*4 + r;
    if (mm < V_) giv[(size_t)mm*H3_ + nn] = acc[r] + bias;
  }
}

// ---------------------------------------------------------------------------
// steps: GRU recurrence, 16 blocks x 768 threads (12 waves).
// Weight stream: 12 chunks/step (36.9 KB each), 4 LDS buffers, prefetch
// depth 3, counted vmcnt(6) waits, NO barriers inside a step (each wave
// reads only the LDS it DMA'd). One raw lgkmcnt+s_barrier per step for the
// fp8 h image (hA). All VMEM counts per wave are deterministic:
//   steady chunk: 3 loads; step epilogue: 2 packed stores (+29 scalar loads
//   at word boundaries) -> waits vmcnt(8)/(37) at c<3, vmcnt(6) at c>=3.
// ---------------------------------------------------------------------------
__global__ __launch_bounds__(768, 1) void steps_kernel(
    const unsigned long long* __restrict__ whh8, const float* __restrict__ giv,
    const float* __restrict__ g01, const float* __restrict__ keys,
    const float* __restrict__ bhh, const int* __restrict__ instr,
    _Float16* __restrict__ hdump)
{
  __shared__ unsigned long long wB[4][4608];   // 4 x 36864 B
  __shared__ unsigned long long hA[768];       // 6144 B fp8 h image

  const int bid = blockIdx.x, b0 = bid*16, tid = threadIdx.x;
  const int w = tid >> 6, lane = tid & 63, m_ = lane & 15, kg = lane >> 4;
  const int c0 = 16*w + m_, c1 = 192 + 16*w + m_;

  float hreg[2][4];
  float bb[6], gvv[4][6], g0r[4], g1r[4];
  int wdr[4];

  #pragma unroll
  for (int g = 0; g < 3; ++g) {
    bb[g*2]   = bhh[g*384 + c0];
    bb[g*2+1] = bhh[g*384 + c1];
  }

  // h0 = tile(scratch_keys[0], 3)
  const float h0a = keys[c0 & 127];
  const float h0b = keys[c1 & 127];
  #pragma unroll
  for (int r = 0; r < 4; ++r) { hreg[0][r] = h0a; hreg[1][r] = h0b; }

  // initial fp8 hA image
  #pragma unroll
  for (int half = 0; half < 2; ++half) {
    const int c = half ? c1 : c0;
    const int base = (c >> 5)*512 + ((c >> 3) & 3)*128 + (c & 7);
    #pragma unroll
    for (int r = 0; r < 4; ++r) {
      __hip_fp8_e4m3 q(hreg[half][r]);
      ((unsigned char*)hA)[base + (kg*4 + r)*8] = q.__x;
    }
  }
  __syncthreads();   // hA visible; vmcnt drained (counts start at 0)

  // ---- word-0 loads: exactly 29 VMEM ops ----
  {
    int4 wd4 = *(const int4*)&instr[(1+0)*B_ + b0 + kg*4];
    wdr[0] = wd4.x; wdr[1] = wd4.y; wdr[2] = wd4.z; wdr[3] = wd4.w;
    #pragma unroll
    for (int r = 0; r < 4; ++r) {
      float2 gg = *(const float2*)&g01[(size_t)(0*B_ + b0 + kg*4 + r)*2];
      g0r[r] = gg.x; g1r[r] = gg.y;
    }
    #pragma unroll
    for (int r = 0; r < 4; ++r) {
      const float* gp = giv + (size_t)wdr[r]*H3_;
      #pragma unroll
      for (int g = 0; g < 3; ++g) {
        gvv[r][g*2]   = gp[g*384 + c0];
        gvv[r][g*2+1] = gp[g*384 + c1];
      }
    }
  }
  SB0();

  // ---- DMA prologue: chunks 0,1,2 -> buffers 0,1,2 (9 ops) ----
  #pragma unroll
  for (int cc = 0; cc < 3; ++cc) {
    const unsigned long long* gs = whh8 + ((size_t)((cc >> 1)*12 + w)*12 + (cc & 1)*6)*64;
    #pragma unroll
    for (int i = 0; i < 3; ++i)
      __builtin_amdgcn_global_load_lds((const unsigned int*)(gs + i*128 + lane*2),
                                       (unsigned int*)&wB[cc][w*384 + i*128], 16, 0, 0);
  }
  SB0();

  // ---- initial h dump, slot 0 (2 packed stores) ----
  #pragma unroll
  for (int half = 0; half < 2; ++half) {
    const int c = half ? c1 : c0;
    half4_t hv;
    #pragma unroll
    for (int r = 0; r < 4; ++r) hv[r] = (_Float16)hreg[half][r];
    *(half4_t*)&hdump[(((size_t)0*16 + bid)*384 + c)*16 + kg*4] = hv;
  }
  SB0();

  #pragma unroll 1
  for (int t = 0; t < 30; ++t) {
    const bool bnd = (t > 0) && (t % 3 == 0);

    // A-fragments from hA (LDS, after barrier)
    unsigned long long av[12];
    #pragma unroll
    for (int ks = 0; ks < 12; ++ks) av[ks] = hA[ks*64 + lane];

    floatx4 acc[6];
    #pragma unroll
    for (int s = 0; s < 6; ++s) acc[s] = (floatx4){0.f, 0.f, 0.f, 0.f};

    #pragma unroll
    for (int c = 0; c < 12; ++c) {
      // counted wait: chunk c's 3 loads retired
      if (c < 3) { if (bnd) VMWAIT(37); else VMWAIT(8); }
      else       { VMWAIT(6); }

      const int s = c >> 1, kh = c & 1;

      // B-fragments for this chunk
      unsigned long long bf[6];
      #pragma unroll
      for (int kcl = 0; kcl < 6; ++kcl)
        bf[kcl] = wB[c & 3][w*384 + kcl*64 + lane];

      // prefetch chunk (c+3)%12 into buffer (c+3)&3  (3 ops)
      {
        const int cn = (c >= 9) ? c - 9 : c + 3;
        const unsigned long long* gs = whh8 + ((size_t)((cn >> 1)*12 + w)*12 + (cn & 1)*6)*64;
        #pragma unroll
        for (int i = 0; i < 3; ++i)
          __builtin_amdgcn_global_load_lds((const unsigned int*)(gs + i*128 + lane*2),
                                           (unsigned int*)&wB[(c+3) & 3][w*384 + i*128], 16, 0, 0);
      }

      #pragma unroll
      for (int kcl = 0; kcl < 6; ++kcl)
        acc[s] = __builtin_amdgcn_mfma_f32_16x16x32_fp8_fp8(
            (long)av[kh*6 + kcl], (long)bf[kcl], acc[s], 0, 0, 0);
      SB0();
    }

    // ---- fused GRU epilogue (wave-local) ----
    #pragma unroll
    for (int half = 0; half < 2; ++half) {
      #pragma unroll
      for (int r = 0; r < 4; ++r) {
        const float ghr = acc[0 + half][r] + bb[0 + half];
        const float ghz = acc[2 + half][r] + bb[2 + half];
        const float ghn = acc[4 + half][r] + bb[4 + half];
        const float rg = 1.f/(1.f + __expf(-(gvv[r][0 + half] + ghr)));
        const float z  = 1.f/(1.f + __expf(-(gvv[r][2 + half] + ghz)));
        const float x2 = gvv[r][4 + half] + rg*ghn;
        const float nn = 2.f/(1.f + __expf(-2.f*x2)) - 1.f;   // tanh
        const float hold = hreg[half][r];
        const float hnew = (1.f - z)*nn + z*hold;
        hreg[half][r] = g0r[r]*hold + g1r[r]*hnew;
      }
    }
    SB0();

    // ---- new fp8 hA image (LDS) + h dump slot t+1 (exactly 2 stores) ----
    #pragma unroll
    for (int half = 0; half < 2; ++half) {
      const int c = half ? c1 : c0;
      const int base = (c >> 5)*512 + ((c >> 3) & 3)*128 + (c & 7);
      half4_t hv;
      #pragma unroll
      for (int r = 0; r < 4; ++r) {
        __hip_fp8_e4m3 q(hreg[half][r]);
        ((unsigned char*)hA)[base + (kg*4 + r)*8] = q.__x;
        hv[r] = (_Float16)hreg[half][r];
      }
      *(half4_t*)&hdump[(((size_t)(t+1)*16 + bid)*384 + c)*16 + kg*4] = hv;
    }
    SB0();

    // ---- word-boundary loads for next word: exactly 29 VMEM ops ----
    if (t % 3 == 2) {
      const int wi = (t/3 + 1 < 10) ? t/3 + 1 : 9;
      int4 wd4 = *(const int4*)&instr[(1+wi)*B_ + b0 + kg*4];
      wdr[0] = wd4.x; wdr[1] = wd4.y; wdr[2] = wd4.z; wdr[3] = wd4.w;
      #pragma unroll
      for (int r = 0; r < 4; ++r) {
        float2 gg = *(const float2*)&g01[((size_t)wi*B_ + b0 + kg*4 + r)*2];
        g0r[r] = gg.x; g1r[r] = gg.y;
      }
      #pragma unroll
      for (int r = 0; r < 4; ++r) {
        const float* gp = giv + (size_t)wdr[r]*H3_;
        #pragma unroll
        for (int g = 0; g < 3; ++g) {
          gvv[r][g*2]   = gp[g*384 + c0];
          gvv[r][g*2+1] = gp[g*384 + c1];
        }
      }
      SB0();
    }

    // raw barrier: LDS visible, DMA stays in flight
    asm volatile("s_waitcnt lgkmcnt(0)\n\ts_barrier" ::: "memory");
  }
  asm volatile("s_waitcnt vmcnt(0) lgkmcnt(0)" ::: "memory");
}

// ---------------------------------------------------------------------------
// attnS: decoupled attention/S recurrence. One block per batch element.
// ---------------------------------------------------------------------------
__global__ __launch_bounds__(256) void attnS_kernel(
    const _Float16* __restrict__ hdump, const float* __restrict__ keys,
    const float* __restrict__ g01, float* __restrict__ S_buf)
{
  __shared__ float keysT[128][52];
  __shared__ float Sr[50][13];
  __shared__ float hrF[256];
  __shared__ float part[4][64];
  __shared__ float pL[64], wmL[64], nvs[12];

  const int b = blockIdx.x, g = b >> 4, bl = b & 15;
  const int tid = threadIdx.x, wv = tid >> 6, lane = tid & 63;

  for (int i = tid; i < 128*L_; i += 256) {
    int k = i / L_, l = i - k*L_;
    keysT[k][l] = keys[l*128 + k];
  }
  for (int i = tid; i < 550; i += 256) Sr[i/11][i%11] = ((i % 11) == 0) ? 1.f : 0.f;
  __syncthreads();

  for (int t = 0; t < 30; ++t) {
    const int widx = t / 3;
    hrF[tid] = (float)hdump[(((size_t)t*16 + g)*384 + 128 + tid)*16 + bl];
    __syncthreads();

    {
      const int ty = wv >> 1, kh = wv & 1;
      float s = 0.f;
      if (lane < L_) {
        #pragma unroll
        for (int k = 0; k < 64; ++k)
          s += hrF[ty*128 + kh*64 + k] * keysT[kh*64 + k][lane];
      }
      part[wv][lane] = s;
    }
    __syncthreads();

    if (wv == 0 || wv == 2) {
      const int ty = wv >> 1;
      float val = (lane < L_) ? part[ty*2][lane] + part[ty*2+1][lane] : -1e30f;
      float mx = val;
      #pragma unroll
      for (int off = 32; off; off >>= 1) mx = fmaxf(mx, __shfl_xor(mx, off));
      float e = (lane < L_) ? __expf(val - mx) : 0.f;
      float sm = e;
      #pragma unroll
      for (int off = 32; off; off >>= 1) sm += __shfl_xor(sm, off);
      if (lane < L_) {
        if (ty == 0) pL[lane] = e / sm; else wmL[lane] = e / sm;
      }
    }
    __syncthreads();

    if (tid < 11) {
      float rv = 0.f;
      #pragma unroll 5
      for (int l = 0; l < L_; ++l) rv += pL[l]*Sr[l][tid];
      const float g0 = g01[(widx*B_ + b)*2 + 0];
      const float g1 = g01[(widx*B_ + b)*2 + 1];
      nvs[tid] = g1*rv + ((tid == 1 + widx) ? g0 : 0.f);
    }
    __syncthreads();

    for (int i = tid; i < 550; i += 256) {
      const int l = i / 11, j = i - l*11;
      Sr[l][j] = wmL[l]*nvs[j] + (1.f - wmL[l])*Sr[l][j];
    }
    __syncthreads();
  }

  for (int i = tid; i < 550; i += 256) {
    const int l = i / 11, j = i - l*11;
    S_buf[(size_t)b*600 + l*12 + j] = Sr[l][j];
  }
}

// ---------------------------------------------------------------------------
// lse: per (b,l) log-sum-exp over the 1000-v reconstruction.
// ---------------------------------------------------------------------------
__global__ __launch_bounds__(512) void lse_kernel(
    const float* __restrict__ S_buf, const float* __restrict__ prim_emb,
    const float* __restrict__ iv_g, const int* __restrict__ instr,
    float* __restrict__ ls_buf)
{
  __shared__ float prim[10][1000];
  __shared__ float iv[1000];
  __shared__ float Sr[50][12];
  __shared__ int wds[10];

  const int b = blockIdx.x;
  const int tid = threadIdx.x;

  if (tid < 10) wds[tid] = instr[(1+tid)*B_ + b];
  for (int i = tid; i < 600; i += 512) Sr[i/12][i%12] = S_buf[(size_t)b*600 + i];
  __syncthreads();
  for (int wi = 0; wi < 10; ++wi) {
    const float4* __restrict__ src = (const float4*)(prim_emb + (size_t)wds[wi]*V_);
    for (int i = tid; i < 250; i += 512) ((float4*)prim[wi])[i] = src[i];
  }
  for (int i = tid; i < 250; i += 512) ((float4*)iv)[i] = ((const float4*)iv_g)[i];
  __syncthreads();

  const int wave = tid >> 6, lane = tid & 63;
  for (int l = wave; l < L_; l += 8) {
    float c0 = Sr[l][0];
    float cw[10];
    #pragma unroll
    for (int wi = 0; wi < 10; ++wi) cw[wi] = Sr[l][1+wi];
    float sv[16];
    float mx = -1e30f;
    #pragma unroll
    for (int j = 0; j < 16; ++j) {
      int v = lane + 64*j;
      float s = -1e30f;
      if (v < V_) {
        s = c0 * iv[v];
        #pragma unroll
        for (int wi = 0; wi < 10; ++wi) s += cw[wi]*prim[wi][v];
      }
      sv[j] = s;
      mx = fmaxf(mx, s);
    }
    #pragma unroll
    for (int off = 32; off; off >>= 1) mx = fmaxf(mx, __shfl_xor(mx, off));
    float se = 0.f;
    #pragma unroll
    for (int j = 0; j < 16; ++j) {
      int v = lane + 64*j;
      if (v < V_) se += __expf(sv[j] - mx);
    }
    #pragma unroll
    for (int off = 32; off; off >>= 1) se += __shfl_xor(se, off);
    if (lane == 0) ls_buf[b*L_ + l] = mx + __logf(se);
  }
}

// ---------------------------------------------------------------------------
// write: per (v-chunk of 125, b) block computes sv - lse, contiguous stores.
// ---------------------------------------------------------------------------
__global__ __launch_bounds__(256) void write_kernel(
    const float* __restrict__ S_buf, const float* __restrict__ prim_emb,
    const float* __restrict__ iv_g, const float* __restrict__ ls_buf,
    const int* __restrict__ instr, float* __restrict__ out)
{
  __shared__ float SrT[11][52];
  __shared__ float lss[52];
  __shared__ float primc[10][128];
  __shared__ float ivc[128];
  __shared__ int wds[10];

  const int cx = blockIdx.x;      // 0..7
  const int b  = blockIdx.y;      // 0..255
  const int v0 = cx * 125;
  const int tid = threadIdx.x;

  if (tid < 10) wds[tid] = instr[(1+tid)*B_ + b];
  if (tid < 50) lss[tid] = ls_buf[b*L_ + tid];
  for (int i = tid; i < 550; i += 256) {
    int l = i / 11, j = i - l*11;
    SrT[j][l] = S_buf[(size_t)b*600 + l*12 + j];
  }
  for (int i = tid; i < 125; i += 256) ivc[i] = iv_g[v0 + i];
  __syncthreads();
  for (int i = tid; i < 1250; i += 256) {
    int wi = i / 125, j = i - wi*125;
    primc[wi][j] = prim_emb[(size_t)wds[wi]*V_ + v0 + j];
  }
  __syncthreads();

  float* __restrict__ dst = out + (size_t)b*50000 + (size_t)v0*50;
  for (int e = tid; e < 125*50; e += 256) {
    const int v = e / 50, l = e - v*50;
    float s = SrT[0][l]*ivc[v];
    #pragma unroll
    for (int wi = 0; wi < 10; ++wi) s += SrT[1+wi][l]*primc[wi][v];
    dst[e] = s - lss[l];
  }
}

// ---------------------------------------------------------------------------
extern "C" void kernel_launch(void* const* d_in, const int* in_sizes, int n_in,
                              void* d_out, int out_size, void* d_ws, size_t ws_size,
                              hipStream_t stream)
{
  (void)in_sizes; (void)n_in; (void)out_size; (void)ws_size;
  const float* gate_emb = (const float*)d_in[0];
  const float* prog_emb = (const float*)d_in[1];
  const float* prim_emb = (const float*)d_in[2];
  const float* sk       = (const float*)d_in[3];
  const float* iv       = (const float*)d_in[4];
  const float* w_ih     = (const float*)d_in[5];
  const float* w_hh     = (const float*)d_in[6];
  const float* b_ih     = (const float*)d_in[7];
  const float* b_hh     = (const float*)d_in[8];
  const int*   instr    = (const int*)d_in[9];
  const int*   tacts    = (const int*)d_in[10];
  float* out = (float*)d_out;

  float* ws     = (float*)d_ws;
  float* S_buf  = ws;                          // 256*600 f32
  float* g01    = S_buf + B_*600;              // 5120 f32
  float* ls_buf = g01 + NW_*B_*2;              // 12800 f32
  float* giv    = ls_buf + B_*L_;              // 1,152,000 f32
  unsigned long long* whh8 = (unsigned long long*)(giv + (size_t)V_*H3_);  // 55296 u64
  _Float16* wih_h  = (_Float16*)(whh8 + 55296);              // 1152*224 f16
  _Float16* prog_h = wih_h + (size_t)H3_*224;                // 200000 f16
  _Float16* hdump  = prog_h + (size_t)V_*P_;                 // 31*16*384*16 f16

  hipLaunchKernelGGL(prep_kernel, dim3(1024), dim3(256), 0, stream,
      gate_emb, prog_emb, w_ih, w_hh, instr, tacts,
      g01, (unsigned char*)whh8, wih_h, prog_h, out);

  hipLaunchKernelGGL(gi_gemm, dim3(63, 18), dim3(256), 0, stream,
      prog_h, wih_h, b_ih, giv);

  hipLaunchKernelGGL(steps_kernel, dim3(16), dim3(768), 0, stream,
      whh8, giv, g01, sk, b_hh, instr, hdump);

  hipLaunchKernelGGL(attnS_kernel, dim3(256), dim3(256), 0, stream,
      hdump, sk, g01, S_buf);

  hipLaunchKernelGGL(lse_kernel, dim3(256), dim3(512), 0, stream,
      S_buf, prim_emb, iv, instr, ls_buf);

  hipLaunchKernelGGL(write_kernel, dim3(8, 256), dim3(256), 0, stream,
      S_buf, prim_emb, iv, ls_buf, instr, out);
}